// Round 1
// baseline (119.963 us; speedup 1.0000x reference)
//
#include <hip/hip_runtime.h>

// DigitCaps dynamic routing — multi-kernel decomposition for occupancy.
// Sync points (global reductions over hw and c) become kernel boundaries:
//   k_init : usum[b,c,q] = sum_hw u ; v1 = squash(0.1*Wm.usum) ; Wv = Wm.v1
//   k_heavy: per (b, hw-chunk): logits = u.Wv, softmax over o,
//            t_chunk[c,o,q] = sum_hw c_ij*u, ps[o,p] = sum_{c,q} Wm.t_chunk
//   k_red  : s = sum_chunks ps ; v = squash(s) ; Wv += Wm.v (or write out)
// Wv accumulates across iterations (b_ij additivity: logits = u . sum Wm.v_it).
// Wv stored transposed [b][o][q][c] for coalesced access both sides.

#define BB 128
#define CC 32
#define HWN 144   // 12*12
#define QQ 8      // IN_CAPS
#define OO 10     // OUT_CH
#define PP 16     // OUT_CAPS
#define NCH 6     // hw chunks
#define CHW 24    // hw per chunk (NCH*CHW == HWN)

__device__ float g_Wv[BB * CC * OO * QQ];     // [b][(o*QQ+q)*CC + c]   1.31 MB
__device__ float g_ps[BB * NCH * OO * PP];    // [b][chunk][o*PP+p]     0.49 MB

// ---------------------------------------------------------------- k_init
__global__ __launch_bounds__(512, 1)
void k_init(const float* __restrict__ x, const float* __restrict__ Wm) {
    const int b = blockIdx.x, tid = threadIdx.x;
    const int c = tid >> 4, slot = tid & 15;   // 32 c * 16 slots
    __shared__ float usum_s[CC * QQ];
    __shared__ float v_s[OO * PP];

    const float* xc = x + ((size_t)b * CC + c) * (HWN * QQ);
    float us[QQ];
#pragma unroll
    for (int q = 0; q < QQ; ++q) us[q] = 0.f;
#pragma unroll
    for (int i = 0; i < 9; ++i) {              // 144 = 16 slots * 9
        const int hw = slot + (i << 4);
        const float4* p4 = (const float4*)(xc + hw * QQ);
        float4 a = p4[0], d = p4[1];
        us[0] += a.x; us[1] += a.y; us[2] += a.z; us[3] += a.w;
        us[4] += d.x; us[5] += d.y; us[6] += d.z; us[7] += d.w;
    }
#pragma unroll
    for (int m = 1; m <= 8; m <<= 1) {
#pragma unroll
        for (int q = 0; q < QQ; ++q) us[q] += __shfl_xor(us[q], m);
    }
    if (slot == 0) {
#pragma unroll
        for (int q = 0; q < QQ; ++q) usum_s[c * QQ + q] = us[q];
    }
    __syncthreads();

    // v1 = squash(0.1 * Wm . usum)
    if (tid < OO * PP) {
        const int o = tid >> 4, p = tid & 15;
        float s = 0.f;
        for (int cc = 0; cc < CC; ++cc) {
            const float4* w4 = (const float4*)(Wm + (((cc * OO + o) * PP + p) * QQ));
            float4 w0 = w4[0], w1 = w4[1];
            const float* u0 = &usum_s[cc * QQ];
            s += w0.x * u0[0] + w0.y * u0[1] + w0.z * u0[2] + w0.w * u0[3]
               + w1.x * u0[4] + w1.y * u0[5] + w1.z * u0[6] + w1.w * u0[7];
        }
        s *= 0.1f;
        float sn = s * s;
#pragma unroll
        for (int m = 1; m <= 8; m <<= 1) sn += __shfl_xor(sn, m);
        const float fac = sqrtf(sn) / (1.f + sn);
        v_s[tid] = s * fac;
    }
    __syncthreads();

    // Wv[b][o][q][c] = sum_p Wm[c,o,p,q] * v1[o,p]   (overwrite: graph-safe)
    if (tid < CC * OO) {
        const int o = tid >> 5, cc = tid & 31;    // coalesced c within wave
        float acc[QQ];
#pragma unroll
        for (int q = 0; q < QQ; ++q) acc[q] = 0.f;
        const float* wp = Wm + ((cc * OO + o) * PP) * QQ;
#pragma unroll
        for (int p = 0; p < PP; ++p) {
            const float vv = v_s[o * PP + p];
            const float4* w4 = (const float4*)(wp + p * QQ);
            float4 w0 = w4[0], w1 = w4[1];
            acc[0] += vv * w0.x; acc[1] += vv * w0.y; acc[2] += vv * w0.z; acc[3] += vv * w0.w;
            acc[4] += vv * w1.x; acc[5] += vv * w1.y; acc[6] += vv * w1.z; acc[7] += vv * w1.w;
        }
        float* wvp = g_Wv + (size_t)b * (CC * OO * QQ);
#pragma unroll
        for (int q = 0; q < QQ; ++q) wvp[(o * QQ + q) * CC + cc] = acc[q];
    }
}

// ---------------------------------------------------------------- k_heavy
__global__ __launch_bounds__(256, 3)
void k_heavy(const float* __restrict__ x, const float* __restrict__ Wm) {
    const int chunk = blockIdx.x;   // 0..5
    const int b     = blockIdx.y;
    const int tid   = threadIdx.x;
    const int c     = tid >> 3;     // 0..31
    const int slot  = tid & 7;      // 0..7

    __shared__ float t_s[CC * OO * QQ];   // [c][o*8+q]

    // logit weights for this c: broadcast over slot, coalesced over c
    const float* wvb = g_Wv + (size_t)b * (CC * OO * QQ);
    float wv[OO][QQ];
#pragma unroll
    for (int o = 0; o < OO; ++o)
#pragma unroll
        for (int q = 0; q < QQ; ++q) wv[o][q] = wvb[(o * QQ + q) * CC + c];

    const float* xc = x + ((size_t)b * CC + c) * (HWN * QQ);
    float tl[OO][QQ];
#pragma unroll
    for (int o = 0; o < OO; ++o)
#pragma unroll
        for (int q = 0; q < QQ; ++q) tl[o][q] = 0.f;

#pragma unroll
    for (int i = 0; i < 3; ++i) {          // 24 hw = 8 slots * 3
        const int hw = chunk * CHW + slot + (i << 3);
        const float4* p4 = (const float4*)(xc + hw * QQ);
        float4 a = p4[0], d = p4[1];
        float u[QQ] = {a.x, a.y, a.z, a.w, d.x, d.y, d.z, d.w};
        float lg[OO];
        float mx = -1e30f;
#pragma unroll
        for (int o = 0; o < OO; ++o) {
            float t = 0.f;
#pragma unroll
            for (int q = 0; q < QQ; ++q) t += u[q] * wv[o][q];
            lg[o] = t;
            mx = fmaxf(mx, t);
        }
        float ssum = 0.f;
#pragma unroll
        for (int o = 0; o < OO; ++o) { lg[o] = __expf(lg[o] - mx); ssum += lg[o]; }
        const float inv = 1.f / ssum;
#pragma unroll
        for (int o = 0; o < OO; ++o) {
            const float cij = lg[o] * inv;
#pragma unroll
            for (int q = 0; q < QQ; ++q) tl[o][q] += cij * u[q];
        }
    }
    // reduce t over the 8 slot lanes
#pragma unroll
    for (int m = 1; m <= 4; m <<= 1) {
#pragma unroll
        for (int o = 0; o < OO; ++o)
#pragma unroll
            for (int q = 0; q < QQ; ++q) tl[o][q] += __shfl_xor(tl[o][q], m);
    }
    if (slot == 0) {
#pragma unroll
        for (int o = 0; o < OO; ++o)
#pragma unroll
            for (int q = 0; q < QQ; ++q) t_s[c * (OO * QQ) + o * QQ + q] = tl[o][q];
    }
    __syncthreads();

    // partial s for this chunk: ps[o,p] = sum_{c,q} Wm[c,o,p,q] * t[c,o,q]
    if (tid < OO * PP) {
        const int o = tid >> 4, p = tid & 15;
        float s = 0.f;
        for (int cc = 0; cc < CC; ++cc) {
            const float4* w4 = (const float4*)(Wm + (((cc * OO + o) * PP + p) * QQ));
            float4 w0 = w4[0], w1 = w4[1];
            const float4* t4 = (const float4*)(t_s + cc * (OO * QQ) + o * QQ);
            float4 t0 = t4[0], t1 = t4[1];
            s += w0.x * t0.x + w0.y * t0.y + w0.z * t0.z + w0.w * t0.w
               + w1.x * t1.x + w1.y * t1.y + w1.z * t1.z + w1.w * t1.w;
        }
        g_ps[((size_t)b * NCH + chunk) * (OO * PP) + tid] = s;
    }
}

// ---------------------------------------------------------------- k_red
template <int FINAL>
__global__ __launch_bounds__(320, 1)
void k_red(const float* __restrict__ Wm, float* __restrict__ out) {
    const int b = blockIdx.x, tid = threadIdx.x;
    __shared__ float v_s[OO * PP];

    if (tid < OO * PP) {
        float s = 0.f;
#pragma unroll
        for (int ch = 0; ch < NCH; ++ch)
            s += g_ps[((size_t)b * NCH + ch) * (OO * PP) + tid];
        float sn = s * s;
#pragma unroll
        for (int m = 1; m <= 8; m <<= 1) sn += __shfl_xor(sn, m);
        const float fac = sqrtf(sn) / (1.f + sn);
        const float v = s * fac;
        if (FINAL) out[(size_t)b * (OO * PP) + tid] = v;
        else       v_s[tid] = v;
    }
    if (!FINAL) {
        __syncthreads();
        // Wv += Wm . v  (logit accumulator across routing iterations)
        if (tid < CC * OO) {
            const int o = tid >> 5, cc = tid & 31;
            float acc[QQ];
#pragma unroll
            for (int q = 0; q < QQ; ++q) acc[q] = 0.f;
            const float* wp = Wm + ((cc * OO + o) * PP) * QQ;
#pragma unroll
            for (int p = 0; p < PP; ++p) {
                const float vv = v_s[o * PP + p];
                const float4* w4 = (const float4*)(wp + p * QQ);
                float4 w0 = w4[0], w1 = w4[1];
                acc[0] += vv * w0.x; acc[1] += vv * w0.y; acc[2] += vv * w0.z; acc[3] += vv * w0.w;
                acc[4] += vv * w1.x; acc[5] += vv * w1.y; acc[6] += vv * w1.z; acc[7] += vv * w1.w;
            }
            float* wvp = g_Wv + (size_t)b * (CC * OO * QQ);
#pragma unroll
            for (int q = 0; q < QQ; ++q) wvp[(o * QQ + q) * CC + cc] += acc[q];
        }
    }
}

extern "C" void kernel_launch(void* const* d_in, const int* in_sizes, int n_in,
                              void* d_out, int out_size, void* d_ws, size_t ws_size,
                              hipStream_t stream) {
    const float* x  = (const float*)d_in[0];   // [128,32,12,12,8]
    const float* Wm = (const float*)d_in[1];   // [1,1,32,10,16,8]
    float* out = (float*)d_out;                // [128,10,16]

    k_init<<<dim3(BB), dim3(512), 0, stream>>>(x, Wm);
    k_heavy<<<dim3(NCH, BB), dim3(256), 0, stream>>>(x, Wm);   // iter 2
    k_red<0><<<dim3(BB), dim3(320), 0, stream>>>(Wm, out);
    k_heavy<<<dim3(NCH, BB), dim3(256), 0, stream>>>(x, Wm);   // iter 3
    k_red<1><<<dim3(BB), dim3(320), 0, stream>>>(Wm, out);
}